// Round 2
// baseline (555.804 us; speedup 1.0000x reference)
//
#include <hip/hip_runtime.h>
#include <stdint.h>

typedef unsigned int u32;
typedef __attribute__((ext_vector_type(8))) short short8;
typedef __attribute__((ext_vector_type(4))) float f32x4;

#define NROWS 8192
#define STRIDE 40   // ushorts per LDS row (32 data + 8 pad = 80B; 80 = 5*16 so b128 rows stay 16B-aligned)

__device__ __forceinline__ float b2f(unsigned short u) {
  return __uint_as_float(((u32)u) << 16);
}
__device__ __forceinline__ unsigned short f2b(float f) {
  u32 i = __float_as_uint(f);
  i += 0x7FFFu + ((i >> 16) & 1u);
  return (unsigned short)(i >> 16);
}

// Shared MFMA inner step: BM=128, BN=128, BK=32. 4 waves, each owns a 64x64
// quadrant (4x4 subtiles of 16x16x32 bf16 MFMA).
#define GEMM_COMPUTE()                                                          \
  {                                                                             \
    short8 afr[4], bfr[4];                                                      \
    _Pragma("unroll") for (int i_ = 0; i_ < 4; ++i_)                            \
      afr[i_] = *(const short8*)(As + (wm + i_*16 + fm)*STRIDE + fq*8);         \
    _Pragma("unroll") for (int j_ = 0; j_ < 4; ++j_)                            \
      bfr[j_] = *(const short8*)(Bs + (wn + j_*16 + fm)*STRIDE + fq*8);         \
    _Pragma("unroll") for (int i_ = 0; i_ < 4; ++i_)                            \
      _Pragma("unroll") for (int j_ = 0; j_ < 4; ++j_)                          \
        acc[i_][j_] = __builtin_amdgcn_mfma_f32_16x16x32_bf16(                  \
            afr[i_], bfr[j_], acc[i_][j_], 0, 0, 0);                            \
  }

// ---------------------------------------------------------------------------
// DETECT: decide whether float tensors are bf16 (flag=1) or fp32 (flag=0).
// For bf16 data, even-indexed ushorts are bf16 normals -> exponent field in a
// narrow band. For fp32 data they are low-mantissa halves -> uniform (~25% in
// band). 256-sample majority vote.
// ---------------------------------------------------------------------------
__global__ void k_detect(const unsigned short* __restrict__ f16, int* __restrict__ flag) {
  __shared__ int cnt;
  if (threadIdx.x == 0) cnt = 0;
  __syncthreads();
  unsigned short u = f16[threadIdx.x * 2];
  int e = (u >> 7) & 0xFF;
  if (e >= 0x60 && e <= 0x9F) atomicAdd(&cnt, 1);
  __syncthreads();
  if (threadIdx.x == 0) *flag = (cnt >= 128) ? 1 : 0;
}

// ---------------------------------------------------------------------------
// PREP: pre-tile F^T, K1^T, K2^T into [k0][row][32] bf16 blocks (dtype-adaptive
// via flag); convert bias/gamma/beta params to fp32 array; zero deg.
// Ft:  [256 k0][128 m=f][32 kk=p]   K1T: [4 k0][256 c][32 kk=f]
// K2T: [8 k0][128 c][32 kk=f]
// par: [b1:256][g1:256][be1:256][b2:128][g2:128][be2:128]
// ---------------------------------------------------------------------------
__global__ void k_prep(const void* __restrict__ featv, const void* __restrict__ K1v,
                       const void* __restrict__ K2v,
                       const void* __restrict__ b1v, const void* __restrict__ g1v,
                       const void* __restrict__ be1v, const void* __restrict__ b2v,
                       const void* __restrict__ g2v, const void* __restrict__ be2v,
                       const int* __restrict__ flagp,
                       unsigned short* __restrict__ Ft,
                       unsigned short* __restrict__ K1T,
                       unsigned short* __restrict__ K2T,
                       float* __restrict__ deg, float* __restrict__ par) {
  const int b = blockIdx.x, t = threadIdx.x;
  const int flag = *flagp;
  if (b < 512) {
    int o = (b*256 + t) << 3;
    int k0 = o >> 12, m = (o >> 5) & 127, kk = o & 31;
    uint4 w;
    if (flag) {
      const unsigned short* s = (const unsigned short*)featv + (size_t)(k0*32 + kk)*128 + m;
      w.x = (u32)s[0]   | ((u32)s[128] << 16);
      w.y = (u32)s[256] | ((u32)s[384] << 16);
      w.z = (u32)s[512] | ((u32)s[640] << 16);
      w.w = (u32)s[768] | ((u32)s[896] << 16);
    } else {
      const float* s = (const float*)featv + (size_t)(k0*32 + kk)*128 + m;
      w.x = (u32)f2b(s[0])   | ((u32)f2b(s[128]) << 16);
      w.y = (u32)f2b(s[256]) | ((u32)f2b(s[384]) << 16);
      w.z = (u32)f2b(s[512]) | ((u32)f2b(s[640]) << 16);
      w.w = (u32)f2b(s[768]) | ((u32)f2b(s[896]) << 16);
    }
    *(uint4*)(Ft + o) = w;
  } else if (b < 528) {
    int o = ((b - 512)*256 + t) << 3;
    int k0 = o >> 13, c = (o >> 5) & 255, kk = o & 31;
    uint4 w;
    if (flag) {
      const unsigned short* s = (const unsigned short*)K1v + (size_t)(k0*32 + kk)*256 + c;
      w.x = (u32)s[0]    | ((u32)s[256]  << 16);
      w.y = (u32)s[512]  | ((u32)s[768]  << 16);
      w.z = (u32)s[1024] | ((u32)s[1280] << 16);
      w.w = (u32)s[1536] | ((u32)s[1792] << 16);
    } else {
      const float* s = (const float*)K1v + (size_t)(k0*32 + kk)*256 + c;
      w.x = (u32)f2b(s[0])    | ((u32)f2b(s[256])  << 16);
      w.y = (u32)f2b(s[512])  | ((u32)f2b(s[768])  << 16);
      w.z = (u32)f2b(s[1024]) | ((u32)f2b(s[1280]) << 16);
      w.w = (u32)f2b(s[1536]) | ((u32)f2b(s[1792]) << 16);
    }
    *(uint4*)(K1T + o) = w;
  } else if (b < 544) {
    int o = ((b - 528)*256 + t) << 3;
    int k0 = o >> 12, c = (o >> 5) & 127, kk = o & 31;
    uint4 w;
    if (flag) {
      const unsigned short* s = (const unsigned short*)K2v + (size_t)(k0*32 + kk)*128 + c;
      w.x = (u32)s[0]   | ((u32)s[128] << 16);
      w.y = (u32)s[256] | ((u32)s[384] << 16);
      w.z = (u32)s[512] | ((u32)s[640] << 16);
      w.w = (u32)s[768] | ((u32)s[896] << 16);
    } else {
      const float* s = (const float*)K2v + (size_t)(k0*32 + kk)*128 + c;
      w.x = (u32)f2b(s[0])   | ((u32)f2b(s[128]) << 16);
      w.y = (u32)f2b(s[256]) | ((u32)f2b(s[384]) << 16);
      w.z = (u32)f2b(s[512]) | ((u32)f2b(s[640]) << 16);
      w.w = (u32)f2b(s[768]) | ((u32)f2b(s[896]) << 16);
    }
    *(uint4*)(K2T + o) = w;
  } else {
    if (t < 256) {
      par[t]       = flag ? b2f(((const unsigned short*)b1v)[t])  : ((const float*)b1v)[t];
      par[256 + t] = flag ? b2f(((const unsigned short*)g1v)[t])  : ((const float*)g1v)[t];
      par[512 + t] = flag ? b2f(((const unsigned short*)be1v)[t]) : ((const float*)be1v)[t];
    }
    if (t < 128) {
      par[768 + t]  = flag ? b2f(((const unsigned short*)b2v)[t])  : ((const float*)b2v)[t];
      par[896 + t]  = flag ? b2f(((const unsigned short*)g2v)[t])  : ((const float*)g2v)[t];
      par[1024 + t] = flag ? b2f(((const unsigned short*)be2v)[t]) : ((const float*)be2v)[t];
    }
    for (int i = t; i < NROWS; i += 256) deg[i] = 0.f;
  }
}

// ---------------------------------------------------------------------------
// GEMM1: C[m=f][n=r] = sum_p Ft[f][p] * adj[p][r].  grid = 64 n-tiles x s1
// k-splits; each split covers ksteps*32 of K. adj 0/1 -> bf16 on the fly,
// column sums (deg) accumulated for free. Output P1[s][r][128 f] fp32.
// ---------------------------------------------------------------------------
__global__ __launch_bounds__(256, 2)
void k_gemm1(const int* __restrict__ adj, const unsigned short* __restrict__ Ft,
             float* __restrict__ P1, float* __restrict__ deg, int ksteps) {
  __shared__ __align__(16) unsigned short As[128*STRIDE];
  __shared__ __align__(16) unsigned short Bs[128*STRIDE];
  __shared__ float degp[128];
  const int t = threadIdx.x;
  const int bx = blockIdx.x;
  const int nt = bx & 63, s = bx >> 6;
  const int n0 = nt << 7;
  const int lane = t & 63, wv = t >> 6;
  const int wm = (wv & 1) << 6, wn = (wv >> 1) << 6;
  const int fm = lane & 15, fq = lane >> 4;
  if (t < 128) degp[t] = 0.0f;
  const f32x4 fzero = {0.f, 0.f, 0.f, 0.f};
  f32x4 acc[4][4];
#pragma unroll
  for (int i = 0; i < 4; ++i)
#pragma unroll
    for (int j = 0; j < 4; ++j) acc[i][j] = fzero;
  int ds0 = 0, ds1 = 0, ds2 = 0, ds3 = 0;
  const int rb = t & 31, kb = t >> 5;
  const int* gB = adj + ((size_t)s*ksteps*32 + kb*4) * NROWS + n0 + rb*4;
  const uint4* gA = (const uint4*)(Ft + (size_t)s*ksteps*4096) + t*2;
  unsigned short* la = As + (t >> 1)*STRIDE + (t & 1)*16;
  unsigned short* lb = Bs + (rb*4)*STRIDE + kb*4;
  for (int ks = 0; ks < ksteps; ++ks) {
    __syncthreads();
    uint4 d0 = gA[0];
    uint4 d1 = gA[1];
    int4 a0 = *(const int4*)(gB);
    int4 a1 = *(const int4*)(gB + NROWS);
    int4 a2 = *(const int4*)(gB + 2*NROWS);
    int4 a3 = *(const int4*)(gB + 3*NROWS);
    gA += 512;
    gB += 32 * NROWS;
    *(uint4*)la = d0;
    *(uint4*)(la + 8) = d1;
    ds0 += a0.x + a1.x + a2.x + a3.x;
    ds1 += a0.y + a1.y + a2.y + a3.y;
    ds2 += a0.z + a1.z + a2.z + a3.z;
    ds3 += a0.w + a1.w + a2.w + a3.w;
    uint2 w;
    w.x = (u32)(a0.x + (a1.x << 16)) * 0x3F80u;
    w.y = (u32)(a2.x + (a3.x << 16)) * 0x3F80u;
    *(uint2*)(lb) = w;
    w.x = (u32)(a0.y + (a1.y << 16)) * 0x3F80u;
    w.y = (u32)(a2.y + (a3.y << 16)) * 0x3F80u;
    *(uint2*)(lb + STRIDE) = w;
    w.x = (u32)(a0.z + (a1.z << 16)) * 0x3F80u;
    w.y = (u32)(a2.z + (a3.z << 16)) * 0x3F80u;
    *(uint2*)(lb + 2*STRIDE) = w;
    w.x = (u32)(a0.w + (a1.w << 16)) * 0x3F80u;
    w.y = (u32)(a2.w + (a3.w << 16)) * 0x3F80u;
    *(uint2*)(lb + 3*STRIDE) = w;
    __syncthreads();
    GEMM_COMPUTE();
  }
  atomicAdd(&degp[rb*4 + 0], (float)ds0);
  atomicAdd(&degp[rb*4 + 1], (float)ds1);
  atomicAdd(&degp[rb*4 + 2], (float)ds2);
  atomicAdd(&degp[rb*4 + 3], (float)ds3);
  float* base = P1 + ((size_t)s * NROWS + n0) * 128;
#pragma unroll
  for (int i = 0; i < 4; ++i)
#pragma unroll
    for (int j = 0; j < 4; ++j) {
      int r = wn + j*16 + fm;
      int f = wm + i*16 + fq*4;
      *(f32x4*)(base + (size_t)r*128 + f) = acc[i][j];
    }
  __syncthreads();
  if (t < 128) atomicAdd(&deg[n0 + t], degp[t]);
}

// ---------------------------------------------------------------------------
// REDUCE1: region0[r][f] = (sum_s P1[s][r][f]) / deg[r] -> bf16 pre-tiled
// [r/128][f/32][128][32]; also invdeg[r]; zeroes BN1 stats.
// ---------------------------------------------------------------------------
__global__ void k_reduce1(const float* __restrict__ P1, const float* __restrict__ deg,
                          unsigned short* __restrict__ R0T, float* __restrict__ invdeg,
                          float* __restrict__ bn1s, float* __restrict__ bn1q, int nsplit) {
  int g = blockIdx.x*256 + threadIdx.x;
  int r = g >> 5;
  int f = (g & 31) << 2;
  f32x4 sum = {0.f, 0.f, 0.f, 0.f};
  for (int s = 0; s < nsplit; ++s)
    sum += *(const f32x4*)(P1 + ((size_t)s*NROWS + r)*128 + f);
  float d = deg[r];
  float inv = (d > 0.5f) ? (1.0f / d) : 0.0f;
  sum *= inv;
  if (f == 0) invdeg[r] = inv;
  uint2 w;
  w.x = (u32)f2b(sum[0]) | ((u32)f2b(sum[1]) << 16);
  w.y = (u32)f2b(sum[2]) | ((u32)f2b(sum[3]) << 16);
  size_t o = ((size_t)(r >> 7)*4 + (f >> 5))*4096 + (size_t)(r & 127)*32 + (f & 31);
  *(uint2*)(R0T + o) = w;
  if (blockIdx.x == 0) { bn1s[threadIdx.x] = 0.f; bn1q[threadIdx.x] = 0.f; }
}

// ---------------------------------------------------------------------------
// PROJ: C = A @ B + bias with fused per-channel sum/sumsq (BN stats). A
// pre-tiled [mt][ks][128][32], B pre-tiled [ks][Ncols][32].
// ---------------------------------------------------------------------------
__global__ __launch_bounds__(256, 2)
void k_proj(const unsigned short* __restrict__ At, const unsigned short* __restrict__ Bt,
            const float* __restrict__ bias, float* __restrict__ Cout,
            float* __restrict__ bns, float* __restrict__ bnq,
            int ksteps, int Ncols) {
  __shared__ __align__(16) unsigned short As[128*STRIDE];
  __shared__ __align__(16) unsigned short Bs[128*STRIDE];
  const int t = threadIdx.x;
  const int bx = blockIdx.x;
  const int mt = bx & 63, ct = bx >> 6;
  const int m0 = mt << 7, n0 = ct << 7;
  const int lane = t & 63, wv = t >> 6;
  const int wm = (wv & 1) << 6, wn = (wv >> 1) << 6;
  const int fm = lane & 15, fq = lane >> 4;
  const f32x4 fzero = {0.f, 0.f, 0.f, 0.f};
  f32x4 acc[4][4];
#pragma unroll
  for (int i = 0; i < 4; ++i)
#pragma unroll
    for (int j = 0; j < 4; ++j) acc[i][j] = fzero;
  const uint4* gA = (const uint4*)(At + (size_t)mt*ksteps*4096) + t*2;
  const uint4* gB = (const uint4*)(Bt + (size_t)n0*32) + t*2;
  const int bstep = Ncols*4;
  unsigned short* la = As + (t >> 1)*STRIDE + (t & 1)*16;
  unsigned short* lb = Bs + (t >> 1)*STRIDE + (t & 1)*16;
  for (int ks = 0; ks < ksteps; ++ks) {
    __syncthreads();
    uint4 a0 = gA[0], a1 = gA[1];
    uint4 b0 = gB[0], b1v = gB[1];
    gA += 512; gB += bstep;
    *(uint4*)la = a0;
    *(uint4*)(la + 8) = a1;
    *(uint4*)lb = b0;
    *(uint4*)(lb + 8) = b1v;
    __syncthreads();
    GEMM_COMPUTE();
  }
#pragma unroll
  for (int j = 0; j < 4; ++j) {
    int c = n0 + wn + j*16 + fm;
    float bc = bias[c];
    float s1 = 0.f, s2 = 0.f;
#pragma unroll
    for (int i = 0; i < 4; ++i) {
      int r = m0 + wm + i*16 + fq*4;
#pragma unroll
      for (int ii = 0; ii < 4; ++ii) {
        float v = acc[i][j][ii] + bc;
        Cout[(size_t)(r + ii)*Ncols + c] = v;
        s1 += v; s2 += v*v;
      }
    }
    s1 += __shfl_xor(s1, 16); s1 += __shfl_xor(s1, 32);
    s2 += __shfl_xor(s2, 16); s2 += __shfl_xor(s2, 32);
    if (fq == 0) { atomicAdd(&bns[c], s1); atomicAdd(&bnq[c], s2); }
  }
}

// ---------------------------------------------------------------------------
// BN1APPLY: Rs[r][c] = BN1(region1)[r][c] * invdeg[r] -> bf16, transposed +
// pre-tiled RsT[k0=r/32][c][r&31].
// ---------------------------------------------------------------------------
__global__ void k_bn1apply(const float* __restrict__ region1, const float* __restrict__ invdeg,
                           const float* __restrict__ bn1s, const float* __restrict__ bn1q,
                           const float* __restrict__ g1, const float* __restrict__ be1,
                           unsigned short* __restrict__ RsT) {
  const int blk = blockIdx.x;
  const int t = threadIdx.x;
  const int r0 = blk << 5;
  const int cg = (t & 63) << 2;
  const int rg0 = (t >> 6) << 2;
  float scale[4], shift[4];
#pragma unroll
  for (int jj = 0; jj < 4; ++jj) {
    int c = cg + jj;
    float mu = bn1s[c] * (1.0f/8192.0f);
    float var = bn1q[c] * (1.0f/8192.0f) - mu*mu;
    float inv = rsqrtf(var + 1e-3f);
    scale[jj] = inv * g1[c];
    shift[jj] = be1[c] - mu * scale[jj];
  }
#pragma unroll
  for (int half = 0; half < 2; ++half) {
    int rg = rg0 + (half << 4);
    f32x4 x[4]; float idg[4];
#pragma unroll
    for (int i = 0; i < 4; ++i) {
      int r = r0 + rg + i;
      x[i] = *(const f32x4*)(region1 + (size_t)r*256 + cg);
      idg[i] = invdeg[r];
    }
#pragma unroll
    for (int jj = 0; jj < 4; ++jj) {
      int c = cg + jj;
      float y0 = (x[0][jj]*scale[jj] + shift[jj]) * idg[0];
      float y1 = (x[1][jj]*scale[jj] + shift[jj]) * idg[1];
      float y2 = (x[2][jj]*scale[jj] + shift[jj]) * idg[2];
      float y3 = (x[3][jj]*scale[jj] + shift[jj]) * idg[3];
      uint2 w;
      w.x = (u32)f2b(y0) | ((u32)f2b(y1) << 16);
      w.y = (u32)f2b(y2) | ((u32)f2b(y3) << 16);
      *(uint2*)(RsT + (size_t)blk*8192 + (size_t)c*32 + rg) = w;
    }
  }
}

// ---------------------------------------------------------------------------
// GEMM2: C[m=p][n=c] = sum_r adj[p][r] * Rs[r][c].  grid = 64 m-tiles x 2
// n-tiles x s2 k-splits. Output P2[s][p][256 c] fp32.
// ---------------------------------------------------------------------------
__global__ __launch_bounds__(256, 2)
void k_gemm2(const int* __restrict__ adj, const unsigned short* __restrict__ RsT,
             float* __restrict__ P2, int ksteps) {
  __shared__ __align__(16) unsigned short As[128*STRIDE];
  __shared__ __align__(16) unsigned short Bs[128*STRIDE];
  const int t = threadIdx.x;
  const int bx = blockIdx.x;
  const int mt = bx & 63, ct = (bx >> 6) & 1, s = bx >> 7;
  const int m0 = mt << 7, n0 = ct << 7;
  const int lane = t & 63, wv = t >> 6;
  const int wm = (wv & 1) << 6, wn = (wv >> 1) << 6;
  const int fm = lane & 15, fq = lane >> 4;
  const f32x4 fzero = {0.f, 0.f, 0.f, 0.f};
  f32x4 acc[4][4];
#pragma unroll
  for (int i = 0; i < 4; ++i)
#pragma unroll
    for (int j = 0; j < 4; ++j) acc[i][j] = fzero;
  const int* gA = adj + (size_t)(m0 + (t >> 1)) * NROWS + s*ksteps*32 + (t & 1)*16;
  const uint4* gB = (const uint4*)(RsT + (size_t)s*ksteps*8192 + n0*32) + t*2;
  unsigned short* la = As + (t >> 1)*STRIDE + (t & 1)*16;
  unsigned short* lb = Bs + (t >> 1)*STRIDE + (t & 1)*16;
  for (int ks = 0; ks < ksteps; ++ks) {
    __syncthreads();
    int4 a0 = *(const int4*)(gA);
    int4 a1 = *(const int4*)(gA + 4);
    int4 a2 = *(const int4*)(gA + 8);
    int4 a3 = *(const int4*)(gA + 12);
    uint4 d0 = gB[0], d1 = gB[1];
    gA += 32; gB += 1024;
    uint4 wa;
    wa.x = (u32)(a0.x + (a0.y << 16)) * 0x3F80u;
    wa.y = (u32)(a0.z + (a0.w << 16)) * 0x3F80u;
    wa.z = (u32)(a1.x + (a1.y << 16)) * 0x3F80u;
    wa.w = (u32)(a1.z + (a1.w << 16)) * 0x3F80u;
    *(uint4*)la = wa;
    wa.x = (u32)(a2.x + (a2.y << 16)) * 0x3F80u;
    wa.y = (u32)(a2.z + (a2.w << 16)) * 0x3F80u;
    wa.z = (u32)(a3.x + (a3.y << 16)) * 0x3F80u;
    wa.w = (u32)(a3.z + (a3.w << 16)) * 0x3F80u;
    *(uint4*)(la + 8) = wa;
    *(uint4*)lb = d0;
    *(uint4*)(lb + 8) = d1;
    __syncthreads();
    GEMM_COMPUTE();
  }
  float* base = P2 + (size_t)s * NROWS * 256;
#pragma unroll
  for (int i = 0; i < 4; ++i)
#pragma unroll
    for (int j = 0; j < 4; ++j) {
      int c = n0 + wn + j*16 + fm;
      int pr = m0 + wm + i*16 + fq*4;
#pragma unroll
      for (int ii = 0; ii < 4; ++ii)
        base[(size_t)(pr + ii)*256 + c] = acc[i][j][ii];
    }
}

// ---------------------------------------------------------------------------
// REDUCE2: people0 = sum_s P2 -> bf16 pre-tiled [p/128][c/32][128][32];
// zeroes BN2 stats.
// ---------------------------------------------------------------------------
__global__ void k_reduce2(const float* __restrict__ P2, unsigned short* __restrict__ P0T,
                          float* __restrict__ bn2s, float* __restrict__ bn2q, int nsplit) {
  int g = blockIdx.x*256 + threadIdx.x;
  int p = g >> 6;
  int c = (g & 63) << 2;
  f32x4 sum = {0.f, 0.f, 0.f, 0.f};
  for (int s = 0; s < nsplit; ++s)
    sum += *(const f32x4*)(P2 + (size_t)s*NROWS*256 + (size_t)p*256 + c);
  uint2 w;
  w.x = (u32)f2b(sum[0]) | ((u32)f2b(sum[1]) << 16);
  w.y = (u32)f2b(sum[2]) | ((u32)f2b(sum[3]) << 16);
  size_t o = ((size_t)(p >> 7)*8 + (c >> 5))*4096 + (size_t)(p & 127)*32 + (c & 31);
  *(uint2*)(P0T + o) = w;
  if (blockIdx.x == 0 && threadIdx.x < 128) {
    bn2s[threadIdx.x] = 0.f; bn2q[threadIdx.x] = 0.f;
  }
}

// ---------------------------------------------------------------------------
// BN2APPLY: out = BN2(people1); output dtype follows detected flag.
// ---------------------------------------------------------------------------
__global__ void k_bn2apply(const float* __restrict__ people1,
                           const float* __restrict__ bn2s, const float* __restrict__ bn2q,
                           const float* __restrict__ g2, const float* __restrict__ be2,
                           void* __restrict__ outv, const int* __restrict__ flagp) {
  int g = blockIdx.x*256 + threadIdx.x;
  int p = g >> 5;
  int c = (g & 31) << 2;
  f32x4 x = *(const f32x4*)(people1 + (size_t)p*128 + c);
  f32x4 y;
#pragma unroll
  for (int jj = 0; jj < 4; ++jj) {
    int cc = c + jj;
    float mu = bn2s[cc] * (1.0f/8192.0f);
    float var = bn2q[cc] * (1.0f/8192.0f) - mu*mu;
    float inv = rsqrtf(var + 1e-3f);
    y[jj] = (x[jj] - mu) * inv * g2[cc] + be2[cc];
  }
  if (*flagp) {
    uint2 w;
    w.x = (u32)f2b(y[0]) | ((u32)f2b(y[1]) << 16);
    w.y = (u32)f2b(y[2]) | ((u32)f2b(y[3]) << 16);
    *(uint2*)((unsigned short*)outv + (size_t)p*128 + c) = w;
  } else {
    *(f32x4*)((float*)outv + (size_t)p*128 + c) = y;
  }
}

// ---------------------------------------------------------------------------
// Workspace layout (ws_size-adaptive), time-multiplexed:
//  A region [0, sizeA):  P1 (s1 x 4MB) -> region1 (8MB) -> C2/P2 (s2 x 8MB)
//                        -> people1 (4MB)
//  B region [sizeA, +4MB): R0T (2MB) -> RsT (4MB) -> P0T (4MB)
//  then Ft (2MB), K1T/K2T (64KB each), deg/invdeg (32KB each), par, bn stats,
//  flag.  (s1,s2) picked so total fits ws_size: (8,4)=38.2MB, (4,2)=22.2MB,
//  (2,1)=14.2MB.
// ---------------------------------------------------------------------------
extern "C" void kernel_launch(void* const* d_in, const int* in_sizes, int n_in,
                              void* d_out, int out_size, void* d_ws, size_t ws_size,
                              hipStream_t stream) {
  const void* feat = d_in[0];
  const int* adj   = (const int*)d_in[1];
  const void* K1   = d_in[2];
  const void* b1   = d_in[3];
  const void* g1   = d_in[4];
  const void* be1  = d_in[5];
  const void* K2   = d_in[6];
  const void* b2   = d_in[7];
  const void* g2   = d_in[8];
  const void* be2  = d_in[9];
  char* ws = (char*)d_ws;
  const size_t MB = 1u << 20;

  const size_t misc = 4*MB /*B*/ + 2*MB /*Ft*/ + 2*65536 /*K1T,K2T*/
                    + 2*32768 /*deg,invdeg*/ + 1152*4 /*par*/ + 768*4 /*bn*/ + 16;
  int s1, s2;
  if (ws_size >= 32*MB + misc)      { s1 = 8; s2 = 4; }
  else if (ws_size >= 16*MB + misc) { s1 = 4; s2 = 2; }
  else                              { s1 = 2; s2 = 1; }
  size_t sizeA = (size_t)(4*s1 > 8*s2 ? 4*s1 : 8*s2);
  if (sizeA < 8) sizeA = 8;
  sizeA *= MB;

  float* P1            = (float*)ws;                 // A region
  float* region1       = (float*)ws;
  float* P2            = (float*)ws;
  float* people1       = (float*)ws;
  char* B              = ws + sizeA;
  unsigned short* R0T  = (unsigned short*)B;
  unsigned short* RsT  = (unsigned short*)B;
  unsigned short* P0T  = (unsigned short*)B;
  unsigned short* Ft   = (unsigned short*)(B + 4*MB);
  unsigned short* K1T  = (unsigned short*)(B + 6*MB);
  unsigned short* K2T  = K1T + 32768;
  float* deg           = (float*)(K2T + 32768);
  float* invdeg        = deg + 8192;
  float* par           = invdeg + 8192;
  float* bn1s          = par + 1152;
  float* bn1q          = bn1s + 256;
  float* bn2s          = bn1q + 256;
  float* bn2q          = bn2s + 128;
  int* flag            = (int*)(bn2q + 128);

  k_detect<<<1, 256, 0, stream>>>((const unsigned short*)feat, flag);
  k_prep<<<545, 256, 0, stream>>>(feat, K1, K2, b1, g1, be1, b2, g2, be2,
                                  flag, Ft, K1T, K2T, deg, par);
  k_gemm1<<<64*s1, 256, 0, stream>>>(adj, Ft, P1, deg, 256/s1);
  k_reduce1<<<1024, 256, 0, stream>>>(P1, deg, R0T, invdeg, bn1s, bn1q, s1);
  k_proj<<<128, 256, 0, stream>>>(R0T, K1T, par + 0, region1, bn1s, bn1q, 4, 256);
  k_bn1apply<<<256, 256, 0, stream>>>(region1, invdeg, bn1s, bn1q, par + 256, par + 512, RsT);
  k_gemm2<<<128*s2, 256, 0, stream>>>(adj, RsT, P2, 256/s2);
  k_reduce2<<<2048, 256, 0, stream>>>(P2, P0T, bn2s, bn2q, s2);
  k_proj<<<64, 256, 0, stream>>>(P0T, K2T, par + 768, people1, bn2s, bn2q, 8, 128);
  k_bn2apply<<<1024, 256, 0, stream>>>(people1, bn2s, bn2q, par + 896, par + 1024, d_out, flag);
}

// Round 3
// 528.052 us; speedup vs baseline: 1.0526x; 1.0526x over previous
//
#include <hip/hip_runtime.h>
#include <stdint.h>

typedef unsigned int u32;
typedef unsigned short u16;
typedef __attribute__((ext_vector_type(8))) short short8;
typedef __attribute__((ext_vector_type(4))) float f32x4;

#define N8K 8192

__device__ __forceinline__ float b2f(u16 u) { return __uint_as_float(((u32)u) << 16); }
__device__ __forceinline__ u16 f2b(float f) {
  u32 i = __float_as_uint(f);
  i += 0x7FFFu + ((i >> 16) & 1u);
  return (u16)(i >> 16);
}
// pack two 0/1 ints into two bf16 halves: (x | y<<16) * 0x3F80 (u24-safe)
__device__ __forceinline__ u32 pk01(int x, int y) { return (u32)__mul24(x | (y << 16), 0x3F80); }
__device__ __forceinline__ u32 pkf(float a, float b) { return (u32)f2b(a) | ((u32)f2b(b) << 16); }

// async global->LDS, 16B per lane; lds dest must be wave-uniform base (+lane*16)
__device__ __forceinline__ void gl_lds16(const void* g, void* l) {
  __builtin_amdgcn_global_load_lds(
      (const __attribute__((address_space(1))) u32*)g,
      (__attribute__((address_space(3))) u32*)l, 16, 0, 0);
}

// 4 waves, each a 64x64 quadrant; 4x4 subtiles of 16x16x32 bf16 MFMA.
#define MFMA_4x4(As_, Bs_, aoff_, boff_)                                         \
  {                                                                              \
    short8 afr[4], bfr[4];                                                       \
    _Pragma("unroll") for (int i_ = 0; i_ < 4; ++i_)                             \
      afr[i_] = *(const short8*)(As_ + aoff_[i_]);                               \
    _Pragma("unroll") for (int j_ = 0; j_ < 4; ++j_)                             \
      bfr[j_] = *(const short8*)(Bs_ + boff_[j_]);                               \
    _Pragma("unroll") for (int i_ = 0; i_ < 4; ++i_)                             \
      _Pragma("unroll") for (int j_ = 0; j_ < 4; ++j_)                           \
        acc[i_][j_] = __builtin_amdgcn_mfma_f32_16x16x32_bf16(                   \
            afr[i_], bfr[j_], acc[i_][j_], 0, 0, 0);                             \
  }

#define ZERO_ACC()                                                               \
  f32x4 acc[4][4];                                                               \
  {                                                                              \
    const f32x4 fz = {0.f, 0.f, 0.f, 0.f};                                       \
    _Pragma("unroll") for (int i_ = 0; i_ < 4; ++i_)                             \
      _Pragma("unroll") for (int j_ = 0; j_ < 4; ++j_) acc[i_][j_] = fz;         \
  }

// ---------------------------------------------------------------------------
// DETECT: bf16 vs fp32 input probe (majority vote on exponent band).
// ---------------------------------------------------------------------------
__global__ void k_detect(const u16* __restrict__ f16, int* __restrict__ flag) {
  __shared__ int cnt;
  if (threadIdx.x == 0) cnt = 0;
  __syncthreads();
  u16 u = f16[threadIdx.x * 2];
  int e = (u >> 7) & 0xFF;
  if (e >= 0x60 && e <= 0x9F) atomicAdd(&cnt, 1);
  __syncthreads();
  if (threadIdx.x == 0) *flag = (cnt >= 128) ? 1 : 0;
}

// ---------------------------------------------------------------------------
// PREP: pre-tile F^T, K1^T, K2^T into [k0][row][32] bf16 blocks; params->fp32;
// zero deg + BN stat arrays.
// Ft:  [256 k0][128 f][32 p]   K1T: [4 k0][256 c][32 f]   K2T: [8 k0][128 c][32 f]
// par: [b1:256][g1:256][be1:256][b2:128][g2:128][be2:128]
// ---------------------------------------------------------------------------
__global__ void k_prep(const void* __restrict__ featv, const void* __restrict__ K1v,
                       const void* __restrict__ K2v,
                       const void* __restrict__ b1v, const void* __restrict__ g1v,
                       const void* __restrict__ be1v, const void* __restrict__ b2v,
                       const void* __restrict__ g2v, const void* __restrict__ be2v,
                       const int* __restrict__ flagp,
                       u16* __restrict__ Ft, u16* __restrict__ K1T, u16* __restrict__ K2T,
                       float* __restrict__ deg, float* __restrict__ par,
                       float* __restrict__ bn1s, float* __restrict__ bn1q,
                       float* __restrict__ bn2s, float* __restrict__ bn2q) {
  const int b = blockIdx.x, t = threadIdx.x;
  const int flag = *flagp;
  if (b < 512) {
    int o = (b * 256 + t) << 3;
    int k0 = o >> 12, m = (o >> 5) & 127, kk = o & 31;
    uint4 w;
    if (flag) {
      const u16* s = (const u16*)featv + (size_t)(k0 * 32 + kk) * 128 + m;
      w.x = (u32)s[0]   | ((u32)s[128] << 16);
      w.y = (u32)s[256] | ((u32)s[384] << 16);
      w.z = (u32)s[512] | ((u32)s[640] << 16);
      w.w = (u32)s[768] | ((u32)s[896] << 16);
    } else {
      const float* s = (const float*)featv + (size_t)(k0 * 32 + kk) * 128 + m;
      w.x = pkf(s[0], s[128]); w.y = pkf(s[256], s[384]);
      w.z = pkf(s[512], s[640]); w.w = pkf(s[768], s[896]);
    }
    *(uint4*)(Ft + o) = w;
  } else if (b < 528) {
    int o = ((b - 512) * 256 + t) << 3;
    int k0 = o >> 13, c = (o >> 5) & 255, kk = o & 31;
    uint4 w;
    if (flag) {
      const u16* s = (const u16*)K1v + (size_t)(k0 * 32 + kk) * 256 + c;
      w.x = (u32)s[0]    | ((u32)s[256]  << 16);
      w.y = (u32)s[512]  | ((u32)s[768]  << 16);
      w.z = (u32)s[1024] | ((u32)s[1280] << 16);
      w.w = (u32)s[1536] | ((u32)s[1792] << 16);
    } else {
      const float* s = (const float*)K1v + (size_t)(k0 * 32 + kk) * 256 + c;
      w.x = pkf(s[0], s[256]); w.y = pkf(s[512], s[768]);
      w.z = pkf(s[1024], s[1280]); w.w = pkf(s[1536], s[1792]);
    }
    *(uint4*)(K1T + o) = w;
  } else if (b < 544) {
    int o = ((b - 528) * 256 + t) << 3;
    int k0 = o >> 12, c = (o >> 5) & 127, kk = o & 31;
    uint4 w;
    if (flag) {
      const u16* s = (const u16*)K2v + (size_t)(k0 * 32 + kk) * 128 + c;
      w.x = (u32)s[0]   | ((u32)s[128] << 16);
      w.y = (u32)s[256] | ((u32)s[384] << 16);
      w.z = (u32)s[512] | ((u32)s[640] << 16);
      w.w = (u32)s[768] | ((u32)s[896] << 16);
    } else {
      const float* s = (const float*)K2v + (size_t)(k0 * 32 + kk) * 128 + c;
      w.x = pkf(s[0], s[128]); w.y = pkf(s[256], s[384]);
      w.z = pkf(s[512], s[640]); w.w = pkf(s[768], s[896]);
    }
    *(uint4*)(K2T + o) = w;
  } else {
    if (t < 256) {
      par[t]       = flag ? b2f(((const u16*)b1v)[t])  : ((const float*)b1v)[t];
      par[256 + t] = flag ? b2f(((const u16*)g1v)[t])  : ((const float*)g1v)[t];
      par[512 + t] = flag ? b2f(((const u16*)be1v)[t]) : ((const float*)be1v)[t];
      bn1s[t] = 0.f; bn1q[t] = 0.f;
    }
    if (t < 128) {
      par[768 + t]  = flag ? b2f(((const u16*)b2v)[t])  : ((const float*)b2v)[t];
      par[896 + t]  = flag ? b2f(((const u16*)g2v)[t])  : ((const float*)g2v)[t];
      par[1024 + t] = flag ? b2f(((const u16*)be2v)[t]) : ((const float*)be2v)[t];
      bn2s[t] = 0.f; bn2q[t] = 0.f;
    }
    for (int i = t; i < N8K; i += 256) deg[i] = 0.f;
  }
}

// ---------------------------------------------------------------------------
// GEMM1: C[m=f][n=r] = sum_p Ft[f][p] * adj[p][r]. grid = 64 n-tiles x 8 splits.
// A(Ft) via global_load_lds; B: adj int4 loads -> pk01 -> swizzled LDS writes.
// deg (col sums) accumulated for free. Output P1[s][r][128 f] fp32.
// ---------------------------------------------------------------------------
__global__ __launch_bounds__(256, 2)
void k_gemm1(const int* __restrict__ adj, const u16* __restrict__ Ft,
             float* __restrict__ P1, float* __restrict__ deg, int ksteps) {
  __shared__ __align__(16) u16 As[128 * 32];
  __shared__ __align__(16) u16 Bs[128 * 32];
  __shared__ float degp[128];
  const int t = threadIdx.x, bx = blockIdx.x;
  const int nt = bx & 63, s = bx >> 6;
  const int n0 = nt << 7;
  const int lane = t & 63, wv = t >> 6;
  const int wm = (wv & 1) << 6, wn = (wv >> 1) << 6;
  const int fm = lane & 15, fq = lane >> 4;
  if (t < 128) degp[t] = 0.0f;
  ZERO_ACC();
  int aoff[4], boff[4];
#pragma unroll
  for (int i = 0; i < 4; ++i) aoff[i] = (wm + i * 16 + fm) * 32 + fq * 8;
#pragma unroll
  for (int j = 0; j < 4; ++j) {
    int n = wn + j * 16 + fm;
    boff[j] = n * 32 + ((fq * 8) ^ (((n >> 2) & 3) << 3));
  }
  const int rb = t & 31, kb = t >> 5;
  const int* gB = adj + ((size_t)s * ksteps * 32 + kb * 4) * N8K + n0 + rb * 4;
  const char* gA = (const char*)(Ft + (size_t)s * ksteps * 4096);
  char* lA = (char*)As + ((t >> 6) << 10);
  const int goff = t << 4;
  u16* lb = Bs + (rb * 4) * 32 + ((kb * 4) ^ ((rb & 3) << 3));
  int ds0 = 0, ds1 = 0, ds2 = 0, ds3 = 0;
  for (int ks = 0; ks < ksteps; ++ks) {
    __syncthreads();
    gl_lds16(gA + goff, lA);
    gl_lds16(gA + 4096 + goff, lA + 4096);
    int4 a0 = *(const int4*)(gB);
    int4 a1 = *(const int4*)(gB + N8K);
    int4 a2 = *(const int4*)(gB + 2 * N8K);
    int4 a3 = *(const int4*)(gB + 3 * N8K);
    gA += 8192;
    gB += 32 * N8K;
    ds0 += a0.x + a1.x + a2.x + a3.x;
    ds1 += a0.y + a1.y + a2.y + a3.y;
    ds2 += a0.z + a1.z + a2.z + a3.z;
    ds3 += a0.w + a1.w + a2.w + a3.w;
    uint2 w;
    w.x = pk01(a0.x, a1.x); w.y = pk01(a2.x, a3.x); *(uint2*)(lb) = w;
    w.x = pk01(a0.y, a1.y); w.y = pk01(a2.y, a3.y); *(uint2*)(lb + 32) = w;
    w.x = pk01(a0.z, a1.z); w.y = pk01(a2.z, a3.z); *(uint2*)(lb + 64) = w;
    w.x = pk01(a0.w, a1.w); w.y = pk01(a2.w, a3.w); *(uint2*)(lb + 96) = w;
    __syncthreads();
    MFMA_4x4(As, Bs, aoff, boff);
  }
  atomicAdd(&degp[rb * 4 + 0], (float)ds0);
  atomicAdd(&degp[rb * 4 + 1], (float)ds1);
  atomicAdd(&degp[rb * 4 + 2], (float)ds2);
  atomicAdd(&degp[rb * 4 + 3], (float)ds3);
  float* base = P1 + ((size_t)s * N8K + n0) * 128;
#pragma unroll
  for (int i = 0; i < 4; ++i)
#pragma unroll
    for (int j = 0; j < 4; ++j) {
      int r = wn + j * 16 + fm;
      int f = wm + i * 16 + fq * 4;
      *(f32x4*)(base + (size_t)r * 128 + f) = acc[i][j];
    }
  __syncthreads();
  if (t < 128) atomicAdd(&deg[n0 + t], degp[t]);
}

// ---------------------------------------------------------------------------
// PROJF: fused (sum split-K partials [*1/deg]) @ B + bias, with BN sum/sumsq.
// A staged from fp32 partials via VALU (swizzled LDS); B via global_load_lds.
// proj1: Psrc=P1 (K=128), Ncols=256, nsplit=8, useinv=1, grid 128.
// proj2: Psrc=P2 (K=256), Ncols=128, nsplit=4, useinv=0, grid 64.
// ---------------------------------------------------------------------------
__global__ __launch_bounds__(256, 2)
void k_projf(const float* __restrict__ Psrc, const float* __restrict__ deg,
             const u16* __restrict__ Bt, const float* __restrict__ bias,
             float* __restrict__ Cout, float* __restrict__ bns, float* __restrict__ bnq,
             int nsplit, int ksteps, int Ncols, int useinv) {
  __shared__ __align__(16) u16 As[128 * 32];
  __shared__ __align__(16) u16 Bs[128 * 32];
  const int t = threadIdx.x, bx = blockIdx.x;
  const int mt = bx & 63, ct = bx >> 6;
  const int m0 = mt << 7, n0 = ct << 7;
  const int lane = t & 63, wv = t >> 6;
  const int wm = (wv & 1) << 6, wn = (wv >> 1) << 6;
  const int fm = lane & 15, fq = lane >> 4;
  const int K = ksteps << 5;
  ZERO_ACC();
  int aoff[4], boff[4];
#pragma unroll
  for (int i = 0; i < 4; ++i) {
    int m = wm + i * 16 + fm;
    aoff[i] = m * 32 + ((fq * 8) ^ (((m >> 2) & 3) << 3));
  }
#pragma unroll
  for (int j = 0; j < 4; ++j) boff[j] = (wn + j * 16 + fm) * 32 + fq * 8;
  const int row = t >> 1;
  const size_t sstride = (size_t)N8K * K;
  const float* src = Psrc + (size_t)(m0 + row) * K + (t & 1) * 16;
  float inv = 1.0f;
  if (useinv) {
    float d = deg[m0 + row];
    inv = (d > 0.5f) ? 1.0f / d : 0.0f;
  }
  const int swzA = ((t >> 3) & 3) << 3;  // ((row>>2)&3)<<3
  u16* la0 = As + row * 32 + (((t & 1) * 16) ^ swzA);
  u16* la1 = As + row * 32 + ((((t & 1) * 16) + 8) ^ swzA);
  char* lB = (char*)Bs + ((t >> 6) << 10);
  const int goff = t << 4;
  for (int ks = 0; ks < ksteps; ++ks) {
    __syncthreads();
    const char* gB = (const char*)(Bt + ((size_t)ks * Ncols + n0) * 32);
    gl_lds16(gB + goff, lB);
    gl_lds16(gB + 4096 + goff, lB + 4096);
    f32x4 s0 = {0.f, 0.f, 0.f, 0.f}, s1 = s0, s2 = s0, s3 = s0;
    const float* p = src + ks * 32;
    for (int sp = 0; sp < nsplit; ++sp) {
      const f32x4* q = (const f32x4*)(p + sp * sstride);
      s0 += q[0]; s1 += q[1]; s2 += q[2]; s3 += q[3];
    }
    s0 *= inv; s1 *= inv; s2 *= inv; s3 *= inv;
    uint4 w;
    w.x = pkf(s0[0], s0[1]); w.y = pkf(s0[2], s0[3]);
    w.z = pkf(s1[0], s1[1]); w.w = pkf(s1[2], s1[3]);
    *(uint4*)la0 = w;
    w.x = pkf(s2[0], s2[1]); w.y = pkf(s2[2], s2[3]);
    w.z = pkf(s3[0], s3[1]); w.w = pkf(s3[2], s3[3]);
    *(uint4*)la1 = w;
    __syncthreads();
    MFMA_4x4(As, Bs, aoff, boff);
  }
#pragma unroll
  for (int j = 0; j < 4; ++j) {
    int c = n0 + wn + j * 16 + fm;
    float bc = bias[c];
    float t1 = 0.f, t2 = 0.f;
#pragma unroll
    for (int i = 0; i < 4; ++i) {
      int r = m0 + wm + i * 16 + fq * 4;
#pragma unroll
      for (int ii = 0; ii < 4; ++ii) {
        float v = acc[i][j][ii] + bc;
        Cout[(size_t)(r + ii) * Ncols + c] = v;
        t1 += v; t2 += v * v;
      }
    }
    t1 += __shfl_xor(t1, 16); t1 += __shfl_xor(t1, 32);
    t2 += __shfl_xor(t2, 16); t2 += __shfl_xor(t2, 32);
    if (fq == 0) { atomicAdd(&bns[c], t1); atomicAdd(&bnq[c], t2); }
  }
}

// ---------------------------------------------------------------------------
// BN1APPLY: Rs[r][c] = BN1(region1)[r][c] / deg[r] -> bf16, transposed +
// pre-tiled RsT[kr=r/32][c 256][r&31].
// ---------------------------------------------------------------------------
__global__ void k_bn1apply(const float* __restrict__ region1, const float* __restrict__ deg,
                           const float* __restrict__ bn1s, const float* __restrict__ bn1q,
                           const float* __restrict__ g1, const float* __restrict__ be1,
                           u16* __restrict__ RsT) {
  const int blk = blockIdx.x;
  const int t = threadIdx.x;
  const int r0 = blk << 5;
  const int cg = (t & 63) << 2;
  const int rg0 = (t >> 6) << 2;
  float scale[4], shift[4];
#pragma unroll
  for (int jj = 0; jj < 4; ++jj) {
    int c = cg + jj;
    float mu = bn1s[c] * (1.0f / 8192.0f);
    float var = bn1q[c] * (1.0f / 8192.0f) - mu * mu;
    float inv = rsqrtf(var + 1e-3f);
    scale[jj] = inv * g1[c];
    shift[jj] = be1[c] - mu * scale[jj];
  }
#pragma unroll
  for (int half = 0; half < 2; ++half) {
    int rg = rg0 + (half << 4);
    f32x4 x[4]; float idg[4];
#pragma unroll
    for (int i = 0; i < 4; ++i) {
      int r = r0 + rg + i;
      x[i] = *(const f32x4*)(region1 + (size_t)r * 256 + cg);
      float d = deg[r];
      idg[i] = (d > 0.5f) ? 1.0f / d : 0.0f;
    }
#pragma unroll
    for (int jj = 0; jj < 4; ++jj) {
      int c = cg + jj;
      float y0 = (x[0][jj] * scale[jj] + shift[jj]) * idg[0];
      float y1 = (x[1][jj] * scale[jj] + shift[jj]) * idg[1];
      float y2 = (x[2][jj] * scale[jj] + shift[jj]) * idg[2];
      float y3 = (x[3][jj] * scale[jj] + shift[jj]) * idg[3];
      uint2 w;
      w.x = pkf(y0, y1);
      w.y = pkf(y2, y3);
      *(uint2*)(RsT + (size_t)blk * 8192 + (size_t)c * 32 + rg) = w;
    }
  }
}

// ---------------------------------------------------------------------------
// GEMM2: C[m=p][n=c] = sum_r adj[p][r] * Rs[r][c]. grid = 64 m x 2 n x 4 splits.
// A: adj int4 (k-contig) -> pk01 -> swizzled LDS; B(RsT) via global_load_lds.
// Output P2[s][p][256 c] fp32.
// ---------------------------------------------------------------------------
__global__ __launch_bounds__(256, 2)
void k_gemm2(const int* __restrict__ adj, const u16* __restrict__ RsT,
             float* __restrict__ P2, int ksteps) {
  __shared__ __align__(16) u16 As[128 * 32];
  __shared__ __align__(16) u16 Bs[128 * 32];
  const int t = threadIdx.x, bx = blockIdx.x;
  const int mt = bx & 63, ct = (bx >> 6) & 1, s = bx >> 7;
  const int m0 = mt << 7, n0 = ct << 7;
  const int lane = t & 63, wv = t >> 6;
  const int wm = (wv & 1) << 6, wn = (wv >> 1) << 6;
  const int fm = lane & 15, fq = lane >> 4;
  ZERO_ACC();
  int aoff[4], boff[4];
#pragma unroll
  for (int i = 0; i < 4; ++i) {
    int m = wm + i * 16 + fm;
    aoff[i] = m * 32 + ((fq * 8) ^ (((m >> 2) & 3) << 3));
  }
#pragma unroll
  for (int j = 0; j < 4; ++j) boff[j] = (wn + j * 16 + fm) * 32 + fq * 8;
  const int* gA = adj + (size_t)(m0 + (t >> 1)) * N8K + (size_t)s * ksteps * 32 + (t & 1) * 16;
  const char* gB = (const char*)(RsT + ((size_t)s * ksteps * 256 + n0) * 32);
  char* lB = (char*)Bs + ((t >> 6) << 10);
  const int goff = t << 4;
  const int swzA = ((t >> 3) & 3) << 3;
  u16* la0 = As + (t >> 1) * 32 + (((t & 1) * 16) ^ swzA);
  u16* la1 = As + (t >> 1) * 32 + ((((t & 1) * 16) + 8) ^ swzA);
  for (int ks = 0; ks < ksteps; ++ks) {
    __syncthreads();
    gl_lds16(gB + goff, lB);
    gl_lds16(gB + 4096 + goff, lB + 4096);
    int4 a0 = *(const int4*)(gA);
    int4 a1 = *(const int4*)(gA + 4);
    int4 a2 = *(const int4*)(gA + 8);
    int4 a3 = *(const int4*)(gA + 12);
    gA += 32;
    gB += 16384;
    uint4 w;
    w.x = pk01(a0.x, a0.y); w.y = pk01(a0.z, a0.w);
    w.z = pk01(a1.x, a1.y); w.w = pk01(a1.z, a1.w);
    *(uint4*)la0 = w;
    w.x = pk01(a2.x, a2.y); w.y = pk01(a2.z, a2.w);
    w.z = pk01(a3.x, a3.y); w.w = pk01(a3.z, a3.w);
    *(uint4*)la1 = w;
    __syncthreads();
    MFMA_4x4(As, Bs, aoff, boff);
  }
  float* base = P2 + (size_t)s * N8K * 256;
#pragma unroll
  for (int i = 0; i < 4; ++i)
#pragma unroll
    for (int j = 0; j < 4; ++j) {
      int c = n0 + wn + j * 16 + fm;
      int pr = m0 + wm + i * 16 + fq * 4;
#pragma unroll
      for (int ii = 0; ii < 4; ++ii)
        base[(size_t)(pr + ii) * 256 + c] = acc[i][j][ii];
    }
}

// ---------------------------------------------------------------------------
// BN2APPLY: out = BN2(people1); output dtype follows detected flag.
// ---------------------------------------------------------------------------
__global__ void k_bn2apply(const float* __restrict__ people1,
                           const float* __restrict__ bn2s, const float* __restrict__ bn2q,
                           const float* __restrict__ g2, const float* __restrict__ be2,
                           void* __restrict__ outv, const int* __restrict__ flagp) {
  int g = blockIdx.x * 256 + threadIdx.x;
  int p = g >> 5;
  int c = (g & 31) << 2;
  f32x4 x = *(const f32x4*)(people1 + (size_t)p * 128 + c);
  f32x4 y;
#pragma unroll
  for (int jj = 0; jj < 4; ++jj) {
    int cc = c + jj;
    float mu = bn2s[cc] * (1.0f / 8192.0f);
    float var = bn2q[cc] * (1.0f / 8192.0f) - mu * mu;
    float inv = rsqrtf(var + 1e-3f);
    y[jj] = (x[jj] - mu) * inv * g2[cc] + be2[cc];
  }
  if (*flagp) {
    uint2 w;
    w.x = pkf(y[0], y[1]);
    w.y = pkf(y[2], y[3]);
    *(uint2*)((u16*)outv + (size_t)p * 128 + c) = w;
  } else {
    *(f32x4*)((float*)outv + (size_t)p * 128 + c) = y;
  }
}

// ---------------------------------------------------------------------------
// Workspace (ws_size ~1GB measured; we use ~50.2MB):
//  [0,32M)   Pbig: P1 (8x4M) then P2 (4x8M)
//  [32M,40M) region1 fp32
//  [40M,44M) people1 fp32
//  [44M,46M) Ft bf16 pre-tiled
//  [46M,50M) RsT bf16 pre-tiled
//  [50M,..)  K1T(64K), K2T(64K), deg(32K), par, bn stats, flag
// ---------------------------------------------------------------------------
extern "C" void kernel_launch(void* const* d_in, const int* in_sizes, int n_in,
                              void* d_out, int out_size, void* d_ws, size_t ws_size,
                              hipStream_t stream) {
  const void* feat = d_in[0];
  const int* adj   = (const int*)d_in[1];
  const void* K1   = d_in[2];
  const void* b1   = d_in[3];
  const void* g1   = d_in[4];
  const void* be1  = d_in[5];
  const void* K2   = d_in[6];
  const void* b2   = d_in[7];
  const void* g2   = d_in[8];
  const void* be2  = d_in[9];
  char* ws = (char*)d_ws;
  const size_t MB = 1u << 20;

  float* Pbig    = (float*)(ws);
  float* region1 = (float*)(ws + 32 * MB);
  float* people1 = (float*)(ws + 40 * MB);
  u16*   Ft      = (u16*)(ws + 44 * MB);
  u16*   RsT     = (u16*)(ws + 46 * MB);
  u16*   K1T     = (u16*)(ws + 50 * MB);
  u16*   K2T     = K1T + 32768;
  float* deg     = (float*)(K2T + 32768);
  float* par     = deg + N8K;
  float* bn1s    = par + 1152;
  float* bn1q    = bn1s + 256;
  float* bn2s    = bn1q + 256;
  float* bn2q    = bn2s + 128;
  int*   flag    = (int*)(bn2q + 128);

  k_detect<<<1, 256, 0, stream>>>((const u16*)feat, flag);
  k_prep<<<545, 256, 0, stream>>>(feat, K1, K2, b1, g1, be1, b2, g2, be2, flag,
                                  Ft, K1T, K2T, deg, par, bn1s, bn1q, bn2s, bn2q);
  k_gemm1<<<512, 256, 0, stream>>>(adj, Ft, Pbig, deg, 32);
  k_projf<<<128, 256, 0, stream>>>(Pbig, deg, K1T, par + 0, region1, bn1s, bn1q,
                                   8, 4, 256, 1);
  k_bn1apply<<<256, 256, 0, stream>>>(region1, deg, bn1s, bn1q, par + 256, par + 512, RsT);
  k_gemm2<<<512, 256, 0, stream>>>(adj, RsT, Pbig, 64);
  k_projf<<<64, 256, 0, stream>>>(Pbig, deg, K2T, par + 768, people1, bn2s, bn2q,
                                  4, 8, 128, 0);
  k_bn2apply<<<1024, 256, 0, stream>>>(people1, bn2s, bn2q, par + 896, par + 1024,
                                       d_out, flag);
}

// Round 4
// 497.615 us; speedup vs baseline: 1.1169x; 1.0612x over previous
//
#include <hip/hip_runtime.h>
#include <stdint.h>

typedef unsigned int u32;
typedef unsigned short u16;
typedef __attribute__((ext_vector_type(8))) short short8;
typedef __attribute__((ext_vector_type(4))) float f32x4;

#define N8K 8192

__device__ __forceinline__ float b2f(u16 u) { return __uint_as_float(((u32)u) << 16); }
__device__ __forceinline__ u16 f2b(float f) {
  u32 i = __float_as_uint(f);
  i += 0x7FFFu + ((i >> 16) & 1u);
  return (u16)(i >> 16);
}
// pack two 0/1 ints into two bf16 halves
__device__ __forceinline__ u32 pk01(int x, int y) { return (u32)__mul24(x | (y << 16), 0x3F80); }
__device__ __forceinline__ u32 pkf(float a, float b) { return (u32)f2b(a) | ((u32)f2b(b) << 16); }

// block-uniform dtype vote: 1 = tensors are bf16, 0 = fp32
__device__ __forceinline__ int dvote(const u16* f16) {
  u16 u = f16[threadIdx.x * 2];
  int e = (u >> 7) & 0xFF;
  return __syncthreads_count((e >= 0x60 && e <= 0x9F) ? 1 : 0) >= 128;
}

// async global->LDS, 16B/lane; lds dest wave-uniform base (+lane*16)
__device__ __forceinline__ void gl_lds16(const void* g, void* l) {
  __builtin_amdgcn_global_load_lds(
      (const __attribute__((address_space(1))) u32*)g,
      (__attribute__((address_space(3))) u32*)l, 16, 0, 0);
}

// 4 waves, each a 64x64 quadrant; 4x4 subtiles of 16x16x32 bf16 MFMA.
#define MFMA_4x4(As_, Bs_, aoff_, boff_)                                         \
  {                                                                              \
    short8 afr[4], bfr[4];                                                       \
    _Pragma("unroll") for (int i_ = 0; i_ < 4; ++i_)                             \
      afr[i_] = *(const short8*)(As_ + aoff_[i_]);                               \
    _Pragma("unroll") for (int j_ = 0; j_ < 4; ++j_)                             \
      bfr[j_] = *(const short8*)(Bs_ + boff_[j_]);                               \
    _Pragma("unroll") for (int i_ = 0; i_ < 4; ++i_)                             \
      _Pragma("unroll") for (int j_ = 0; j_ < 4; ++j_)                           \
        acc[i_][j_] = __builtin_amdgcn_mfma_f32_16x16x32_bf16(                   \
            afr[i_], bfr[j_], acc[i_][j_], 0, 0, 0);                             \
  }

#define ZERO_ACC()                                                               \
  f32x4 acc[4][4];                                                               \
  {                                                                              \
    const f32x4 fz = {0.f, 0.f, 0.f, 0.f};                                       \
    _Pragma("unroll") for (int i_ = 0; i_ < 4; ++i_)                             \
      _Pragma("unroll") for (int j_ = 0; j_ < 4; ++j_) acc[i_][j_] = fz;         \
  }

// ---------------------------------------------------------------------------
// PREP: Ft via coalesced LDS-tile transpose; K1T/K2T gathers; params->fp32;
// zero deg + BN stats.
// Ft:  [256 k0][128 f][32 p]  K1T: [4 k0][256 c][32 f]  K2T: [8 k0][128 c][32 f]
// par: [b1:256][g1:256][be1:256][b2:128][g2:128][be2:128]
// ---------------------------------------------------------------------------
__global__ void k_prep(const void* __restrict__ featv, const void* __restrict__ K1v,
                       const void* __restrict__ K2v,
                       const void* __restrict__ b1v, const void* __restrict__ g1v,
                       const void* __restrict__ be1v, const void* __restrict__ b2v,
                       const void* __restrict__ g2v, const void* __restrict__ be2v,
                       u16* __restrict__ Ft, u16* __restrict__ K1T, u16* __restrict__ K2T,
                       float* __restrict__ deg, float* __restrict__ par,
                       float* __restrict__ bn1s, float* __restrict__ bn1q,
                       float* __restrict__ bn2s, float* __restrict__ bn2q) {
  const int b = blockIdx.x, t = threadIdx.x;
  const int flag = dvote((const u16*)featv);
  if (b < 256) {
    // feat [8192 p][128 f] -> Ft[k0=p/32][f][p&31], via LDS tile
    __shared__ __align__(16) u16 Ls[32 * 136];
    const int pr = t >> 3, ck = t & 7;   // row-in-tile, 16-f chunk
    u16 v[16];
    if (flag) {
      const u16* s = (const u16*)featv + (size_t)(b * 32 + pr) * 128 + ck * 16;
      uint4 a = *(const uint4*)(s);
      uint4 bq = *(const uint4*)(s + 8);
      *(uint4*)&v[0] = a; *(uint4*)&v[8] = bq;
    } else {
      const float* s = (const float*)featv + (size_t)(b * 32 + pr) * 128 + ck * 16;
#pragma unroll
      for (int i = 0; i < 16; ++i) v[i] = f2b(s[i]);
    }
    *(uint4*)(Ls + pr * 136 + ck * 16) = *(uint4*)&v[0];
    *(uint4*)(Ls + pr * 136 + ck * 16 + 8) = *(uint4*)&v[8];
    __syncthreads();
    const int f = t >> 1, h16 = (t & 1) * 16;
    u32 w[8];
#pragma unroll
    for (int i = 0; i < 8; ++i) {
      u16 lo = Ls[(h16 + 2 * i) * 136 + f];
      u16 hi = Ls[(h16 + 2 * i + 1) * 136 + f];
      w[i] = (u32)lo | ((u32)hi << 16);
    }
    u16* d = Ft + (size_t)b * 4096 + f * 32 + h16;
    *(uint4*)(d) = *(uint4*)&w[0];
    *(uint4*)(d + 8) = *(uint4*)&w[4];
  } else if (b < 272) {
    int o = ((b - 256) * 256 + t) << 3;
    int k0 = o >> 13, c = (o >> 5) & 255, kk = o & 31;
    uint4 w;
    if (flag) {
      const u16* s = (const u16*)K1v + (size_t)(k0 * 32 + kk) * 256 + c;
      w.x = (u32)s[0]    | ((u32)s[256]  << 16);
      w.y = (u32)s[512]  | ((u32)s[768]  << 16);
      w.z = (u32)s[1024] | ((u32)s[1280] << 16);
      w.w = (u32)s[1536] | ((u32)s[1792] << 16);
    } else {
      const float* s = (const float*)K1v + (size_t)(k0 * 32 + kk) * 256 + c;
      w.x = pkf(s[0], s[256]); w.y = pkf(s[512], s[768]);
      w.z = pkf(s[1024], s[1280]); w.w = pkf(s[1536], s[1792]);
    }
    *(uint4*)(K1T + o) = w;
  } else if (b < 288) {
    int o = ((b - 272) * 256 + t) << 3;
    int k0 = o >> 12, c = (o >> 5) & 127, kk = o & 31;
    uint4 w;
    if (flag) {
      const u16* s = (const u16*)K2v + (size_t)(k0 * 32 + kk) * 128 + c;
      w.x = (u32)s[0]   | ((u32)s[128] << 16);
      w.y = (u32)s[256] | ((u32)s[384] << 16);
      w.z = (u32)s[512] | ((u32)s[640] << 16);
      w.w = (u32)s[768] | ((u32)s[896] << 16);
    } else {
      const float* s = (const float*)K2v + (size_t)(k0 * 32 + kk) * 128 + c;
      w.x = pkf(s[0], s[128]); w.y = pkf(s[256], s[384]);
      w.z = pkf(s[512], s[640]); w.w = pkf(s[768], s[896]);
    }
    *(uint4*)(K2T + o) = w;
  } else {
    if (t < 256) {
      par[t]       = flag ? b2f(((const u16*)b1v)[t])  : ((const float*)b1v)[t];
      par[256 + t] = flag ? b2f(((const u16*)g1v)[t])  : ((const float*)g1v)[t];
      par[512 + t] = flag ? b2f(((const u16*)be1v)[t]) : ((const float*)be1v)[t];
      bn1s[t] = 0.f; bn1q[t] = 0.f;
    }
    if (t < 128) {
      par[768 + t]  = flag ? b2f(((const u16*)b2v)[t])  : ((const float*)b2v)[t];
      par[896 + t]  = flag ? b2f(((const u16*)g2v)[t])  : ((const float*)g2v)[t];
      par[1024 + t] = flag ? b2f(((const u16*)be2v)[t]) : ((const float*)be2v)[t];
      bn2s[t] = 0.f; bn2q[t] = 0.f;
    }
    for (int i = t; i < N8K; i += 256) deg[i] = 0.f;
  }
}

// ---------------------------------------------------------------------------
// GEMM1: C[m=f][n=r] = sum_p Ft[f][p] * adj[p][r]. grid = 64 n-tiles x 8 splits.
// A(Ft) via global_load_lds; B: adj int4 -> pk01 -> swizzled LDS. deg for free.
// Output P1[s][r][128 f] fp32.
// ---------------------------------------------------------------------------
__global__ __launch_bounds__(256, 2)
void k_gemm1(const int* __restrict__ adj, const u16* __restrict__ Ft,
             float* __restrict__ P1, float* __restrict__ deg, int ksteps) {
  __shared__ __align__(16) u16 As[128 * 32];
  __shared__ __align__(16) u16 Bs[128 * 32];
  __shared__ float degp[128];
  const int t = threadIdx.x, bx = blockIdx.x;
  const int nt = bx & 63, s = bx >> 6;
  const int n0 = nt << 7;
  const int lane = t & 63, wv = t >> 6;
  const int wm = (wv & 1) << 6, wn = (wv >> 1) << 6;
  const int fm = lane & 15, fq = lane >> 4;
  if (t < 128) degp[t] = 0.0f;
  ZERO_ACC();
  int aoff[4], boff[4];
#pragma unroll
  for (int i = 0; i < 4; ++i) aoff[i] = (wm + i * 16 + fm) * 32 + fq * 8;
#pragma unroll
  for (int j = 0; j < 4; ++j) {
    int n = wn + j * 16 + fm;
    boff[j] = n * 32 + ((fq * 8) ^ (((n >> 2) & 3) << 3));
  }
  const int rb = t & 31, kb = t >> 5;
  const int* gB = adj + ((size_t)s * ksteps * 32 + kb * 4) * N8K + n0 + rb * 4;
  const char* gA = (const char*)(Ft + (size_t)s * ksteps * 4096);
  char* lA = (char*)As + ((t >> 6) << 10);
  const int goff = t << 4;
  u16* lb = Bs + (rb * 4) * 32 + ((kb * 4) ^ ((rb & 3) << 3));
  int ds0 = 0, ds1 = 0, ds2 = 0, ds3 = 0;
  for (int ks = 0; ks < ksteps; ++ks) {
    __syncthreads();
    gl_lds16(gA + goff, lA);
    gl_lds16(gA + 4096 + goff, lA + 4096);
    int4 a0 = *(const int4*)(gB);
    int4 a1 = *(const int4*)(gB + N8K);
    int4 a2 = *(const int4*)(gB + 2 * N8K);
    int4 a3 = *(const int4*)(gB + 3 * N8K);
    gA += 8192;
    gB += 32 * N8K;
    ds0 += a0.x + a1.x + a2.x + a3.x;
    ds1 += a0.y + a1.y + a2.y + a3.y;
    ds2 += a0.z + a1.z + a2.z + a3.z;
    ds3 += a0.w + a1.w + a2.w + a3.w;
    uint2 w;
    w.x = pk01(a0.x, a1.x); w.y = pk01(a2.x, a3.x); *(uint2*)(lb) = w;
    w.x = pk01(a0.y, a1.y); w.y = pk01(a2.y, a3.y); *(uint2*)(lb + 32) = w;
    w.x = pk01(a0.z, a1.z); w.y = pk01(a2.z, a3.z); *(uint2*)(lb + 64) = w;
    w.x = pk01(a0.w, a1.w); w.y = pk01(a2.w, a3.w); *(uint2*)(lb + 96) = w;
    __syncthreads();
    MFMA_4x4(As, Bs, aoff, boff);
  }
  atomicAdd(&degp[rb * 4 + 0], (float)ds0);
  atomicAdd(&degp[rb * 4 + 1], (float)ds1);
  atomicAdd(&degp[rb * 4 + 2], (float)ds2);
  atomicAdd(&degp[rb * 4 + 3], (float)ds3);
  float* base = P1 + ((size_t)s * N8K + n0) * 128;
#pragma unroll
  for (int i = 0; i < 4; ++i)
#pragma unroll
    for (int j = 0; j < 4; ++j) {
      int r = wn + j * 16 + fm;
      int f = wm + i * 16 + fq * 4;
      *(f32x4*)(base + (size_t)r * 128 + f) = acc[i][j];
    }
  __syncthreads();
  if (t < 128) atomicAdd(&deg[n0 + t], degp[t]);
}

// ---------------------------------------------------------------------------
// PROJF1: region1 = (sum_s P1 * invdeg) @ K1 + b1, fused BN1 sum/sumsq.
// grid 128 = 64 mt x 2 ct (ct in low bit for adjacent-block L2 reuse of P1).
// ---------------------------------------------------------------------------
__global__ __launch_bounds__(256, 2)
void k_projf(const float* __restrict__ Psrc, const float* __restrict__ deg,
             const u16* __restrict__ Bt, const float* __restrict__ bias,
             float* __restrict__ Cout, float* __restrict__ bns, float* __restrict__ bnq,
             int nsplit, int ksteps, int Ncols, int useinv) {
  __shared__ __align__(16) u16 As[128 * 32];
  __shared__ __align__(16) u16 Bs[128 * 32];
  const int t = threadIdx.x, bx = blockIdx.x;
  const int ct = bx & 1, mt = (bx >> 1) & 63;
  const int m0 = mt << 7, n0 = ct << 7;
  const int lane = t & 63, wv = t >> 6;
  const int wm = (wv & 1) << 6, wn = (wv >> 1) << 6;
  const int fm = lane & 15, fq = lane >> 4;
  const int K = ksteps << 5;
  ZERO_ACC();
  int aoff[4], boff[4];
#pragma unroll
  for (int i = 0; i < 4; ++i) {
    int m = wm + i * 16 + fm;
    aoff[i] = m * 32 + ((fq * 8) ^ (((m >> 2) & 3) << 3));
  }
#pragma unroll
  for (int j = 0; j < 4; ++j) boff[j] = (wn + j * 16 + fm) * 32 + fq * 8;
  const int row = t >> 1;
  const size_t sstride = (size_t)N8K * K;
  const float* src = Psrc + (size_t)(m0 + row) * K + (t & 1) * 16;
  float inv = 1.0f;
  if (useinv) {
    float d = deg[m0 + row];
    inv = (d > 0.5f) ? 1.0f / d : 0.0f;
  }
  const int swzA = ((t >> 3) & 3) << 3;
  u16* la0 = As + row * 32 + (((t & 1) * 16) ^ swzA);
  u16* la1 = As + row * 32 + ((((t & 1) * 16) + 8) ^ swzA);
  char* lB = (char*)Bs + ((t >> 6) << 10);
  const int goff = t << 4;
  for (int ks = 0; ks < ksteps; ++ks) {
    __syncthreads();
    const char* gB = (const char*)(Bt + ((size_t)ks * Ncols + n0) * 32);
    gl_lds16(gB + goff, lB);
    gl_lds16(gB + 4096 + goff, lB + 4096);
    f32x4 s0 = {0.f, 0.f, 0.f, 0.f}, s1 = s0, s2 = s0, s3 = s0;
    const float* p = src + ks * 32;
    for (int sp = 0; sp < nsplit; ++sp) {
      const f32x4* q = (const f32x4*)(p + sp * sstride);
      s0 += q[0]; s1 += q[1]; s2 += q[2]; s3 += q[3];
    }
    s0 *= inv; s1 *= inv; s2 *= inv; s3 *= inv;
    uint4 w;
    w.x = pkf(s0[0], s0[1]); w.y = pkf(s0[2], s0[3]);
    w.z = pkf(s1[0], s1[1]); w.w = pkf(s1[2], s1[3]);
    *(uint4*)la0 = w;
    w.x = pkf(s2[0], s2[1]); w.y = pkf(s2[2], s2[3]);
    w.z = pkf(s3[0], s3[1]); w.w = pkf(s3[2], s3[3]);
    *(uint4*)la1 = w;
    __syncthreads();
    MFMA_4x4(As, Bs, aoff, boff);
  }
#pragma unroll
  for (int j = 0; j < 4; ++j) {
    int c = n0 + wn + j * 16 + fm;
    float bc = bias[c];
    float t1 = 0.f, t2 = 0.f;
#pragma unroll
    for (int i = 0; i < 4; ++i) {
      int r = m0 + wm + i * 16 + fq * 4;
#pragma unroll
      for (int ii = 0; ii < 4; ++ii) {
        float v = acc[i][j][ii] + bc;
        Cout[(size_t)(r + ii) * Ncols + c] = v;
        t1 += v; t2 += v * v;
      }
    }
    t1 += __shfl_xor(t1, 16); t1 += __shfl_xor(t1, 32);
    t2 += __shfl_xor(t2, 16); t2 += __shfl_xor(t2, 32);
    if (fq == 0) { atomicAdd(&bns[c], t1); atomicAdd(&bnq[c], t2); }
  }
}

// ---------------------------------------------------------------------------
// BNH: H = (BN1(region1)*invdeg) @ K2, fused. grid 64 mt. K=256 (8 ksteps),
// N=128. A staged on-the-fly from fp32 region1 (BN applied in registers);
// B(K2T) via global_load_lds. Epilogue writes H transposed+pre-tiled
// HT[r/32][128 c][r&31] bf16 (gemm2 B-layout).
// ---------------------------------------------------------------------------
__global__ __launch_bounds__(256, 2)
void k_bnH(const float* __restrict__ region1, const float* __restrict__ deg,
           const float* __restrict__ bn1s, const float* __restrict__ bn1q,
           const float* __restrict__ g1, const float* __restrict__ be1,
           const u16* __restrict__ K2T, u16* __restrict__ HT) {
  __shared__ __align__(16) u16 As[128 * 32];
  __shared__ __align__(16) u16 Bs[128 * 32];
  __shared__ float scS[256], shS[256];
  const int t = threadIdx.x, mt = blockIdx.x;
  const int m0 = mt << 7;
  const int lane = t & 63, wv = t >> 6;
  const int wm = (wv & 1) << 6, wn = (wv >> 1) << 6;
  const int fm = lane & 15, fq = lane >> 4;
  // per-channel BN1 scale/shift into LDS (once)
  {
    float mu = bn1s[t] * (1.0f / 8192.0f);
    float var = bn1q[t] * (1.0f / 8192.0f) - mu * mu;
    float iv = rsqrtf(var + 1e-3f);
    float sc = iv * g1[t];
    scS[t] = sc;
    shS[t] = be1[t] - mu * sc;
  }
  ZERO_ACC();
  int aoff[4], boff[4];
#pragma unroll
  for (int i = 0; i < 4; ++i) {
    int m = wm + i * 16 + fm;
    aoff[i] = m * 32 + ((fq * 8) ^ (((m >> 2) & 3) << 3));
  }
#pragma unroll
  for (int j = 0; j < 4; ++j) boff[j] = (wn + j * 16 + fm) * 32 + fq * 8;
  const int row = t >> 1, half = t & 1;
  float d = deg[m0 + row];
  const float idg = (d > 0.5f) ? 1.0f / d : 0.0f;
  const float* src = region1 + (size_t)(m0 + row) * 256 + half * 16;
  const int swzA = ((t >> 3) & 3) << 3;
  u16* la0 = As + row * 32 + ((half * 16) ^ swzA);
  u16* la1 = As + row * 32 + (((half * 16) + 8) ^ swzA);
  char* lB = (char*)Bs + ((t >> 6) << 10);
  const int goff = t << 4;
  for (int ks = 0; ks < 8; ++ks) {
    __syncthreads();
    const char* gB = (const char*)(K2T + (size_t)ks * 4096);
    gl_lds16(gB + goff, lB);
    gl_lds16(gB + 4096 + goff, lB + 4096);
    const float* p = src + ks * 32;
    const int cb = ks * 32 + half * 16;
    float y[16];
#pragma unroll
    for (int q = 0; q < 4; ++q) {
      f32x4 x = *(const f32x4*)(p + q * 4);
#pragma unroll
      for (int jj = 0; jj < 4; ++jj)
        y[q * 4 + jj] = (x[jj] * scS[cb + q * 4 + jj] + shS[cb + q * 4 + jj]) * idg;
    }
    uint4 w;
    w.x = pkf(y[0], y[1]); w.y = pkf(y[2], y[3]);
    w.z = pkf(y[4], y[5]); w.w = pkf(y[6], y[7]);
    *(uint4*)la0 = w;
    w.x = pkf(y[8], y[9]); w.y = pkf(y[10], y[11]);
    w.z = pkf(y[12], y[13]); w.w = pkf(y[14], y[15]);
    *(uint4*)la1 = w;
    __syncthreads();
    MFMA_4x4(As, Bs, aoff, boff);
  }
  // write HT[r>>5][c][r&31]
#pragma unroll
  for (int i = 0; i < 4; ++i)
#pragma unroll
    for (int j = 0; j < 4; ++j) {
      int c = wn + j * 16 + fm;
      int r = m0 + wm + i * 16 + fq * 4;
      uint2 w;
      w.x = pkf(acc[i][j][0], acc[i][j][1]);
      w.y = pkf(acc[i][j][2], acc[i][j][3]);
      *(uint2*)(HT + (size_t)(r >> 5) * 4096 + c * 32 + (r & 31)) = w;
    }
}

// ---------------------------------------------------------------------------
// GEMM2: C[m=p][n=c] = sum_r adj[p][r] * H[r][c]. grid = 64 mt x 8 splits,
// BN=128 = full width (adj read once). A: adj -> pk01 -> swizzled LDS;
// B(HT) via global_load_lds. Output P2[s][p][128 c] fp32.
// ---------------------------------------------------------------------------
__global__ __launch_bounds__(256, 2)
void k_gemm2(const int* __restrict__ adj, const u16* __restrict__ HT,
             float* __restrict__ P2, int ksteps) {
  __shared__ __align__(16) u16 As[128 * 32];
  __shared__ __align__(16) u16 Bs[128 * 32];
  const int t = threadIdx.x, bx = blockIdx.x;
  const int mt = bx & 63, s = bx >> 6;
  const int m0 = mt << 7;
  const int lane = t & 63, wv = t >> 6;
  const int wm = (wv & 1) << 6, wn = (wv >> 1) << 6;
  const int fm = lane & 15, fq = lane >> 4;
  ZERO_ACC();
  int aoff[4], boff[4];
#pragma unroll
  for (int i = 0; i < 4; ++i) {
    int m = wm + i * 16 + fm;
    aoff[i] = m * 32 + ((fq * 8) ^ (((m >> 2) & 3) << 3));
  }
#pragma unroll
  for (int j = 0; j < 4; ++j) boff[j] = (wn + j * 16 + fm) * 32 + fq * 8;
  const int row = t >> 1, half = t & 1;
  const int* gA = adj + (size_t)(m0 + row) * N8K + (size_t)s * ksteps * 32 + half * 16;
  const char* gB = (const char*)(HT + (size_t)s * ksteps * 4096);
  char* lB = (char*)Bs + ((t >> 6) << 10);
  const int goff = t << 4;
  const int swzA = ((t >> 3) & 3) << 3;
  u16* la0 = As + row * 32 + ((half * 16) ^ swzA);
  u16* la1 = As + row * 32 + (((half * 16) + 8) ^ swzA);
  for (int ks = 0; ks < ksteps; ++ks) {
    __syncthreads();
    gl_lds16(gB + goff, lB);
    gl_lds16(gB + 4096 + goff, lB + 4096);
    int4 a0 = *(const int4*)(gA);
    int4 a1 = *(const int4*)(gA + 4);
    int4 a2 = *(const int4*)(gA + 8);
    int4 a3 = *(const int4*)(gA + 12);
    gA += 32;
    gB += 8192;
    uint4 w;
    w.x = pk01(a0.x, a0.y); w.y = pk01(a0.z, a0.w);
    w.z = pk01(a1.x, a1.y); w.w = pk01(a1.z, a1.w);
    *(uint4*)la0 = w;
    w.x = pk01(a2.x, a2.y); w.y = pk01(a2.z, a2.w);
    w.z = pk01(a3.x, a3.y); w.w = pk01(a3.z, a3.w);
    *(uint4*)la1 = w;
    __syncthreads();
    MFMA_4x4(As, Bs, aoff, boff);
  }
  float* base = P2 + (size_t)s * N8K * 128;
#pragma unroll
  for (int i = 0; i < 4; ++i)
#pragma unroll
    for (int j = 0; j < 4; ++j) {
      int c = wn + j * 16 + fm;
      int pr = m0 + wm + i * 16 + fq * 4;
#pragma unroll
      for (int ii = 0; ii < 4; ++ii)
        base[(size_t)(pr + ii) * 128 + c] = acc[i][j][ii];
    }
}

// ---------------------------------------------------------------------------
// RED2: people1 = sum_s P2 + b2, fused BN2 sum/sumsq stats. grid 256 (32 rows).
// ---------------------------------------------------------------------------
__global__ void k_red2(const float* __restrict__ P2, const float* __restrict__ bias,
                       float* __restrict__ people1,
                       float* __restrict__ bn2s, float* __restrict__ bn2q) {
  __shared__ float r1[256], r2[256];
  const int t = threadIdx.x;
  const int c = t & 127, pg = t >> 7;
  const int p0 = blockIdx.x << 5;
  const float bc = bias[c];
  float s1 = 0.f, s2 = 0.f;
  for (int pp = pg; pp < 32; pp += 2) {
    size_t o = (size_t)(p0 + pp) * 128 + c;
    float v = bc;
#pragma unroll
    for (int s = 0; s < 8; ++s) v += P2[(size_t)s * N8K * 128 + o];
    people1[o] = v;
    s1 += v; s2 += v * v;
  }
  r1[t] = s1; r2[t] = s2;
  __syncthreads();
  if (t < 128) {
    atomicAdd(&bn2s[t], r1[t] + r1[t + 128]);
    atomicAdd(&bn2q[t], r2[t] + r2[t + 128]);
  }
}

// ---------------------------------------------------------------------------
// BN2APPLY: out = BN2(people1); output dtype via per-block vote on feat.
// ---------------------------------------------------------------------------
__global__ void k_bn2apply(const float* __restrict__ people1,
                           const float* __restrict__ bn2s, const float* __restrict__ bn2q,
                           const float* __restrict__ g2, const float* __restrict__ be2,
                           const u16* __restrict__ featprobe, void* __restrict__ outv) {
  const int flag = dvote(featprobe);
  int g = blockIdx.x * 256 + threadIdx.x;
  int p = g >> 5;
  int c = (g & 31) << 2;
  f32x4 x = *(const f32x4*)(people1 + (size_t)p * 128 + c);
  f32x4 y;
#pragma unroll
  for (int jj = 0; jj < 4; ++jj) {
    int cc = c + jj;
    float mu = bn2s[cc] * (1.0f / 8192.0f);
    float var = bn2q[cc] * (1.0f / 8192.0f) - mu * mu;
    float inv = rsqrtf(var + 1e-3f);
    y[jj] = (x[jj] - mu) * inv * g2[cc] + be2[cc];
  }
  if (flag) {
    uint2 w;
    w.x = pkf(y[0], y[1]);
    w.y = pkf(y[2], y[3]);
    *(uint2*)((u16*)outv + (size_t)p * 128 + c) = w;
  } else {
    *(f32x4*)((float*)outv + (size_t)p * 128 + c) = y;
  }
}

// ---------------------------------------------------------------------------
// Workspace (~48.3 MB):
//  [0,32M)   Pbig: P1 (8 x 4MB) then P2 (8 x 4MB)
//  [32M,40M) region1 fp32
//  [40M,44M) people1 fp32
//  [44M,46M) Ft bf16   [46M,48M) HT bf16
//  [48M,..)  K1T(64K), K2T(64K), deg(32K), par, bn stats
// ---------------------------------------------------------------------------
extern "C" void kernel_launch(void* const* d_in, const int* in_sizes, int n_in,
                              void* d_out, int out_size, void* d_ws, size_t ws_size,
                              hipStream_t stream) {
  const void* feat = d_in[0];
  const int* adj   = (const int*)d_in[1];
  const void* K1   = d_in[2];
  const void* b1   = d_in[3];
  const void* g1   = d_in[4];
  const void* be1  = d_in[5];
  const void* K2   = d_in[6];
  const void* b2   = d_in[7];
  const void* g2   = d_in[8];
  const void* be2  = d_in[9];
  char* ws = (char*)d_ws;
  const size_t MB = 1u << 20;

  float* Pbig    = (float*)(ws);
  float* region1 = (float*)(ws + 32 * MB);
  float* people1 = (float*)(ws + 40 * MB);
  u16*   Ft      = (u16*)(ws + 44 * MB);
  u16*   HT      = (u16*)(ws + 46 * MB);
  u16*   K1T     = (u16*)(ws + 48 * MB);
  u16*   K2T     = K1T + 32768;
  float* deg     = (float*)(K2T + 32768);
  float* par     = deg + N8K;
  float* bn1s    = par + 1152;
  float* bn1q    = bn1s + 256;
  float* bn2s    = bn1q + 256;
  float* bn2q    = bn2s + 128;

  k_prep<<<289, 256, 0, stream>>>(feat, K1, K2, b1, g1, be1, b2, g2, be2,
                                  Ft, K1T, K2T, deg, par, bn1s, bn1q, bn2s, bn2q);
  k_gemm1<<<512, 256, 0, stream>>>(adj, Ft, Pbig, deg, 32);
  k_projf<<<128, 256, 0, stream>>>(Pbig, deg, K1T, par + 0, region1, bn1s, bn1q,
                                   8, 4, 256, 1);
  k_bnH<<<64, 256, 0, stream>>>(region1, deg, bn1s, bn1q, par + 256, par + 512,
                                K2T, HT);
  k_gemm2<<<512, 256, 0, stream>>>(adj, HT, Pbig, 32);
  k_red2<<<256, 256, 0, stream>>>(Pbig, par + 768, people1, bn2s, bn2q);
  k_bn2apply<<<1024, 256, 0, stream>>>(people1, bn2s, bn2q, par + 896, par + 1024,
                                       (const u16*)feat, d_out);
}